// Round 10
// baseline (178.671 us; speedup 1.0000x reference)
//
#include <hip/hip_runtime.h>
#include <hip/hip_bf16.h>
#include <stdint.h>
#include <stddef.h>

typedef __bf16 bf16;
typedef float f32x4 __attribute__((ext_vector_type(4)));
typedef bf16 bf16x8 __attribute__((ext_vector_type(8)));
typedef bf16 bf16x4 __attribute__((ext_vector_type(4)));

#define MROWS 8192
#define NOUT 256
#define BM 32
#define BK 128      // compute K-step
#define PSTEPS 4    // K-steps per staged panel
#define PK (BK * PSTEPS)  // 512 floats per row per panel
#define NTHREADS 512

#define SLOT_BYTES (BM * PK * 2)      // 32 KiB panel slot (bf16), x2 = 64 KiB
#define LDS_SMALL (BM * BK * 2)       // 8 KiB for the small-K kernel

#define SCHED0 __builtin_amdgcn_sched_barrier(0)
#define SBAR __builtin_amdgcn_s_barrier()

// ---------------------------------------------------------------------------
// Bp fragment-permuted layout (unchanged): for K-step ts, wave w, frag
// (bfi,ak), lane l, 16-byte chunk at byte (ts*64 + w*8 + bfi*4 + ak)*1024 +
// l*16, holding B[n][k0..k0+7], n = w*32+bfi*16+(l&15), k0 = ts*128+ak*32+
// (l>>4)*8.  Producer map for (n,k): ts=k>>7, w=n>>5, bfi=(n>>4)&1,
// ak=(k>>5)&3, l=((k>>3)&3)*16+(n&15), byte=(k&7)*2.
// ---------------------------------------------------------------------------

// ============== panelized big-K kernel (K % 512 == 0, NP >= 3) ==============
// Round-9 vmcnt-decoupled schedule + NEW: per-block K-phase stagger.
// Accumulation commutes, so block b walks panels in rotated order
// pp = (p + b) % NP. This spreads the chip's instantaneous A addresses over
// the full 32KB row stride (all DRAM channels) instead of the whole chip
// hammering one 2KB k-window in lockstep.
template <bool SCALE, bool OUTT>
__global__ __launch_bounds__(NTHREADS, 1) void gemm_big(
    const float* __restrict__ A, const bf16* __restrict__ Bp,
    const float* __restrict__ filt, void* __restrict__ outp,
    const int K, const int lda) {
  __shared__ char lds[2][SLOT_BYTES];
  const int t = threadIdx.x;
  const int w = t >> 6;
  const int l = t & 63;
  const int m0 = blockIdx.x * BM;
  const int NT = K / BK;
  const int NP = K / PK;
  const int ofs = (int)blockIdx.x % NP;  // per-block K-phase

  // physical K-step for logical step lt (lt already wrapped into [0,NT))
  auto physTS = [&](int lt) -> int {
    int pp = (lt >> 2) + ofs;
    if (pp >= NP) pp -= NP;
    return (pp << 2) + (lt & 3);
  };

  // ---- A staging: wave w owns rows w*4..w*4+3. Op q (0..7): row w*4+(q>>1),
  // float col (q&1)*256 + l*4 (dense 1KB wave burst)
  const float* gAw = A + (size_t)(m0 + w * 4) * (size_t)lda + l * 4;

  // ds_write (b64) offsets: element (r, cf) at byte r*1024 + ((cf*2)^((r&7)<<4))
  int awoff[8];
#pragma unroll
  for (int q = 0; q < 8; ++q) {
    const int r = w * 4 + (q >> 1);
    awoff[q] = r * 1024 + ((((q & 1) * 512) + l * 8) ^ ((r & 7) << 4));
  }

  // ---- A fragment read offsets: step s adds s*256 (disjoint bits from XOR)
  int aoff0[2][4];
#pragma unroll
  for (int af = 0; af < 2; ++af)
#pragma unroll
    for (int ak = 0; ak < 4; ++ak) {
      const int r = af * 16 + (l & 15);
      aoff0[af][ak] = r * 1024 + ((ak * 64 + (l >> 4) * 16) ^ ((r & 7) << 4));
    }

  const char* pBw = (const char*)Bp + w * 8192 + l * 16;

  f32x4 acc[2][2] = {};
  f32x4 pA[8];
  bf16x8 Breg[4][2][4];

  // ================= prologue =================
  // logical panel 0 = physical panel ofs -> pA
  {
    const float* gAp0 = gAw + (size_t)ofs * PK;
#pragma unroll
    for (int q = 0; q < 8; ++q)
      pA[q] = __builtin_nontemporal_load(
          (const f32x4*)(gAp0 + (size_t)(q >> 1) * lda + (q & 1) * 256));
  }
  SCHED0;
  // B(logical 0) -> set0, B(logical 1) -> set1
  {
    const size_t kb0 = (size_t)physTS(0) << 16;
    const size_t kb1 = (size_t)physTS(1) << 16;
#pragma unroll
    for (int bfi = 0; bfi < 2; ++bfi)
#pragma unroll
      for (int ak = 0; ak < 4; ++ak) {
        Breg[0][bfi][ak] = *(const bf16x8*)(pBw + kb0 + (bfi * 4 + ak) * 1024);
        Breg[1][bfi][ak] = *(const bf16x8*)(pBw + kb1 + (bfi * 4 + ak) * 1024);
      }
  }
  SCHED0;
  // cvt + write logical panel 0 -> slot 0 (vmcnt waits only the pA loads)
#pragma unroll
  for (int q = 0; q < 8; ++q) {
    bf16x4 pk;
#pragma unroll
    for (int e = 0; e < 4; ++e) pk[e] = (bf16)pA[q][e];
    *(bf16x4*)(lds[0] + awoff[q]) = pk;
  }
  SCHED0;
  // logical panel 1 -> pA (stays in flight across the barrier)
  {
    int pp1 = ofs + 1;
    if (pp1 >= NP) pp1 -= NP;
    const float* gAp1 = gAw + (size_t)pp1 * PK;
#pragma unroll
    for (int q = 0; q < 8; ++q)
      pA[q] = __builtin_nontemporal_load(
          (const f32x4*)(gAp1 + (size_t)(q >> 1) * lda + (q & 1) * 256));
  }
  asm volatile("s_waitcnt lgkmcnt(0)" ::: "memory");
  SBAR;
  SCHED0;

  // ================= main loop: NP logical panels x 4 steps =================
  for (int p = 0; p < NP; ++p) {
    const char* rslot = lds[p & 1];
    char* wslot = lds[(p + 1) & 1];
    int pp2 = p + 2 + ofs;
    pp2 %= NP;  // physical panel for logical p+2 (tail wraps to dummy)
    const float* gApn2 = gAw + (size_t)pp2 * PK;

#pragma unroll
    for (int s = 0; s < PSTEPS; ++s) {
      const int ts = p * PSTEPS + s;
      if (s == 0) {
        // write logical panel p+1 into the slot freed by the p-1 barrier
#pragma unroll
        for (int q = 0; q < 8; ++q) {
          bf16x4 pk;
#pragma unroll
          for (int e = 0; e < 4; ++e) pk[e] = (bf16)pA[q][e];
          *(bf16x4*)(wslot + awoff[q]) = pk;
        }
        SCHED0;
      }
      // B(logical ts+2) -> Breg[(s+2)&3] (depth-2 prefetch)
      {
        int lt2 = ts + 2;
        if (lt2 >= NT) lt2 -= NT;  // tail: dummy (never consumed)
        const size_t kb2 = (size_t)physTS(lt2) << 16;
#pragma unroll
        for (int bfi = 0; bfi < 2; ++bfi)
#pragma unroll
          for (int ak = 0; ak < 4; ++ak)
            Breg[(s + 2) & 3][bfi][ak] =
                *(const bf16x8*)(pBw + kb2 + (bfi * 4 + ak) * 1024);
      }
      SCHED0;
      // A loads for logical panel p+2: 4 dense 1KB ops at s=0, 4 at s=1
      if (s < 2) {
#pragma unroll
        for (int q4 = 0; q4 < 4; ++q4) {
          const int q = s * 4 + q4;
          pA[q] = __builtin_nontemporal_load(
              (const f32x4*)(gApn2 + (size_t)(q >> 1) * lda + (q & 1) * 256));
        }
        SCHED0;
      }
      // fragments + MFMA (consumes Breg[s&3] = B(phys(p,s)), matching the
      // A-fragments of physical panel (p+ofs)%NP)
      bf16x8 afr[2][4];
#pragma unroll
      for (int af = 0; af < 2; ++af)
#pragma unroll
        for (int ak = 0; ak < 4; ++ak)
          afr[af][ak] = *(const bf16x8*)(rslot + aoff0[af][ak] + s * 256);
      __builtin_amdgcn_s_setprio(1);
#pragma unroll
      for (int ak = 0; ak < 4; ++ak)
#pragma unroll
        for (int af = 0; af < 2; ++af)
#pragma unroll
          for (int bfi = 0; bfi < 2; ++bfi)
            acc[af][bfi] = __builtin_amdgcn_mfma_f32_16x16x32_bf16(
                afr[af][ak], Breg[s & 3][bfi][ak], acc[af][bfi], 0, 0, 0);
      __builtin_amdgcn_s_setprio(0);
    }
    asm volatile("s_waitcnt lgkmcnt(0)" ::: "memory");
    SBAR;
  }

  // ---- epilogue (C/D: col = lane&15, row = (lane>>4)*4 + reg)
#pragma unroll
  for (int af = 0; af < 2; ++af)
#pragma unroll
    for (int bfi = 0; bfi < 2; ++bfi) {
      const int mb = m0 + af * 16 + (l >> 4) * 4;
      const int n = w * 32 + bfi * 16 + (l & 15);
      f32x4 v = acc[af][bfi];
      if (SCALE) {
#pragma unroll
        for (int j = 0; j < 4; ++j) v[j] *= filt[mb + j];
      }
      if (OUTT) {
        bf16x4 pv;
#pragma unroll
        for (int j = 0; j < 4; ++j) pv[j] = (bf16)v[j];
        const int tsq = mb >> 7, wq = n >> 5, bq = (n >> 4) & 1, aq = (mb >> 5) & 3;
        const int lq = ((mb >> 3) & 3) * 16 + (n & 15);
        char* dst = (char*)outp +
                    (size_t)(((tsq * 64 + wq * 8 + bq * 4 + aq) << 10) + lq * 16 +
                             (mb & 7) * 2);
        *(bf16x4*)dst = pv;
      } else {
        float* po = (float*)outp + (size_t)mb * NOUT + n;
#pragma unroll
        for (int j = 0; j < 4; ++j) po[(size_t)j * NOUT] = v[j];
      }
    }
}

// ======================= small-K kernel (round-4 schedule, NT>=2) ===========
template <bool SCALE, bool OUTT>
__global__ __launch_bounds__(NTHREADS, 1) void gemm_small(
    const float* __restrict__ A, const bf16* __restrict__ Bp,
    const float* __restrict__ filt, void* __restrict__ outp,
    const int K, const int lda) {
  __shared__ char lds[2][LDS_SMALL];
  const int t = threadIdx.x;
  const int w = t >> 6;
  const int l = t & 63;
  const int m0 = blockIdx.x * BM;
  const int NT = K / BK;

  const int ar = t >> 4;
  const int acb = t & 15;
  const float* gA = A + (size_t)(m0 + ar) * (size_t)lda + acb * 8;
  const int a_lds_off = (ar * (BK * 2) + acb * 16) ^ ((ar & 7) << 4);

  int aoff[2][4];
#pragma unroll
  for (int af = 0; af < 2; ++af)
#pragma unroll
    for (int ak = 0; ak < 4; ++ak) {
      const int r = af * 16 + (l & 15);
      const int kb = ak * 64 + (l >> 4) * 16;
      aoff[af][ak] = (r * (BK * 2) + kb) ^ ((r & 7) << 4);
    }

  const char* pBw = (const char*)Bp + w * 8192 + l * 16;

  f32x4 acc[2][2] = {};

  f32x4 aS0a = __builtin_nontemporal_load((const f32x4*)gA);
  f32x4 aS0b = __builtin_nontemporal_load((const f32x4*)gA + 1);
  f32x4 aS1a = __builtin_nontemporal_load((const f32x4*)(gA + BK));
  f32x4 aS1b = __builtin_nontemporal_load((const f32x4*)(gA + BK) + 1);
  bf16x8 Bc[2][4], Bn[2][4];
#pragma unroll
  for (int bfi = 0; bfi < 2; ++bfi)
#pragma unroll
    for (int ak = 0; ak < 4; ++ak)
      Bc[bfi][ak] = *(const bf16x8*)(pBw + (bfi * 4 + ak) * 1024);
  {
    bf16x8 pk;
#pragma unroll
    for (int j = 0; j < 4; ++j) { pk[j] = (bf16)aS0a[j]; pk[j + 4] = (bf16)aS0b[j]; }
    *(bf16x8*)(lds[0] + a_lds_off) = pk;
  }
  asm volatile("s_waitcnt lgkmcnt(0)" ::: "memory");
  SBAR;
  SCHED0;

#define BODY_S(TS, P, BCUR, BNXT, AW0, AW1, AL0, AL1)                         \
  {                                                                           \
    const char* bb = lds[P];                                                  \
    bf16x8 afr[2][4];                                                         \
    _Pragma("unroll") for (int af = 0; af < 2; ++af)                          \
        _Pragma("unroll") for (int ak = 0; ak < 4; ++ak)                      \
            afr[af][ak] = *(const bf16x8*)(bb + aoff[af][ak]);                \
    SCHED0;                                                                   \
    const size_t kb1 = (size_t)((((TS) + 1) < NT ? ((TS) + 1) : 0)) << 16;    \
    _Pragma("unroll") for (int bfi = 0; bfi < 2; ++bfi)                       \
        _Pragma("unroll") for (int ak = 0; ak < 4; ++ak)                      \
            BNXT[bfi][ak] =                                                   \
                *(const bf16x8*)(pBw + kb1 + (bfi * 4 + ak) * 1024);          \
    SCHED0;                                                                   \
    const int ka2 = (((TS) + 2) < NT ? ((TS) + 2) : 0) * BK;                  \
    AL0 = __builtin_nontemporal_load((const f32x4*)(gA + ka2));               \
    AL1 = __builtin_nontemporal_load((const f32x4*)(gA + ka2) + 1);           \
    SCHED0;                                                                   \
    asm volatile("s_waitcnt lgkmcnt(0)" ::: "memory");                        \
    SCHED0;                                                                   \
    __builtin_amdgcn_s_setprio(1);                                            \
    _Pragma("unroll") for (int ak = 0; ak < 4; ++ak)                          \
        _Pragma("unroll") for (int af = 0; af < 2; ++af)                      \
            _Pragma("unroll") for (int bfi = 0; bfi < 2; ++bfi)               \
                acc[af][bfi] = __builtin_amdgcn_mfma_f32_16x16x32_bf16(       \
                    afr[af][ak], BCUR[bfi][ak], acc[af][bfi], 0, 0, 0);       \
    __builtin_amdgcn_s_setprio(0);                                            \
    SCHED0;                                                                   \
    {                                                                         \
      bf16x8 pk;                                                              \
      _Pragma("unroll") for (int j = 0; j < 4; ++j) {                         \
        pk[j] = (bf16)AW0[j];                                                 \
        pk[j + 4] = (bf16)AW1[j];                                             \
      }                                                                       \
      *(bf16x8*)(lds[P ^ 1] + a_lds_off) = pk;                                \
    }                                                                         \
    asm volatile("s_waitcnt lgkmcnt(0)" ::: "memory");                        \
    SBAR;                                                                     \
    SCHED0;                                                                   \
  }

  for (int ts = 0; ts < NT; ts += 2) {
    BODY_S(ts, 0, Bc, Bn, aS1a, aS1b, aS0a, aS0b);
    BODY_S(ts + 1, 1, Bn, Bc, aS0a, aS0b, aS1a, aS1b);
  }
#undef BODY_S

#pragma unroll
  for (int af = 0; af < 2; ++af)
#pragma unroll
    for (int bfi = 0; bfi < 2; ++bfi) {
      const int mb = m0 + af * 16 + (l >> 4) * 4;
      const int n = w * 32 + bfi * 16 + (l & 15);
      f32x4 v = acc[af][bfi];
      if (SCALE) {
#pragma unroll
        for (int j = 0; j < 4; ++j) v[j] *= filt[mb + j];
      }
      if (OUTT) {
        bf16x4 pv;
#pragma unroll
        for (int j = 0; j < 4; ++j) pv[j] = (bf16)v[j];
        const int tsq = mb >> 7, wq = n >> 5, bq = (n >> 4) & 1, aq = (mb >> 5) & 3;
        const int lq = ((mb >> 3) & 3) * 16 + (n & 15);
        char* dst = (char*)outp +
                    (size_t)(((tsq * 64 + wq * 8 + bq * 4 + aq) << 10) + lq * 16 +
                             (mb & 7) * 2);
        *(bf16x4*)dst = pv;
      } else {
        float* po = (float*)outp + (size_t)mb * NOUT + n;
#pragma unroll
        for (int j = 0; j < 4; ++j) po[(size_t)j * NOUT] = v[j];
      }
    }
}

// W [256 k][256 n] fp32 -> Wp bf16 in Bp layout
__global__ void prep_wt(const float* __restrict__ W, bf16* __restrict__ Wp) {
  const int k = blockIdx.x;
  const int n = threadIdx.x;
  const int off = (((k >> 7) * 64 + (n >> 5) * 8 + ((n >> 4) & 1) * 4 +
                    ((k >> 5) & 3)) << 10) +
                  (((k >> 3) & 3) * 16 + (n & 15)) * 16 + (k & 7) * 2;
  *(bf16*)((char*)Wp + off) = (bf16)W[k * 256 + n];
}

extern "C" void kernel_launch(void* const* d_in, const int* in_sizes, int n_in,
                              void* d_out, int out_size, void* d_ws, size_t ws_size,
                              hipStream_t stream) {
  const float* features = (const float*)d_in[0];
  const float* wavelets = (const float*)d_in[1];
  const float* wavelets_inv = (const float*)d_in[2];
  const float* W = (const float*)d_in[3];
  const float* filt = (const float*)d_in[4];
  float* out = (float*)d_out;

  char* ws = (char*)d_ws;
  bf16* Wp = (bf16*)ws;                       // 128 KiB, Bp layout (K=256)
  bf16* Tp = (bf16*)(ws + 131072);            // 4 MiB, Bp layout (K=8192)
  bf16* Fp = (bf16*)(ws + 131072 + 4194304);  // 4 MiB, Bp layout (K=8192)

  prep_wt<<<256, 256, 0, stream>>>(W, Wp);
  gemm_small<false, true><<<256, NTHREADS, 0, stream>>>(features, Wp, nullptr, Tp, 256, 256);
  gemm_big<true, true><<<256, NTHREADS, 0, stream>>>(wavelets_inv, Tp, filt, Fp, 8192, 8192);
  gemm_big<false, false><<<256, NTHREADS, 0, stream>>>(wavelets, Fp, nullptr, out, 8192, 8192);
}